// Round 4
// baseline (141.513 us; speedup 1.0000x reference)
//
#include <hip/hip_runtime.h>
#include <hip/hip_bf16.h>

typedef unsigned short u16;
typedef __attribute__((ext_vector_type(8))) short short8v;    // 8 x bf16 (4 VGPR) MFMA A/B frag
typedef __attribute__((ext_vector_type(8))) unsigned short ushort8v;
typedef __attribute__((ext_vector_type(4))) float f32x4;      // MFMA C/D frag

#define GLOBAL_AS __attribute__((address_space(1)))
#define LDS_AS    __attribute__((address_space(3)))

__device__ __forceinline__ void gload_lds16(const void* g, void* l) {
    // 16B/lane direct global->LDS (dest = wave-uniform base + lane*16)
    __builtin_amdgcn_global_load_lds((const GLOBAL_AS unsigned int*)g,
                                     (LDS_AS unsigned int*)l, 16, 0, 0);
}

// ---------------- x: f32 -> bf16 (RNE) ----------------
__global__ __launch_bounds__(256) void conv_x_kernel(const float* __restrict__ X,
                                                     u16* __restrict__ Xb, int n8) {
    int i = blockIdx.x * 256 + threadIdx.x;   // one thread = 8 elements
    if (i >= n8) return;
    const float4* src = (const float4*)X + (size_t)i * 2;
    float4 a = src[0], b = src[1];
    float v[8] = {a.x, a.y, a.z, a.w, b.x, b.y, b.z, b.w};
    ushort8v o;
#pragma unroll
    for (int j = 0; j < 8; ++j) {
        unsigned int u = __builtin_bit_cast(unsigned int, v[j]);
        u += 0x7FFFu + ((u >> 16) & 1u);      // round-to-nearest-even
        o[j] = (u16)(u >> 16);
    }
    *((ushort8v*)Xb + i) = o;
}

// ---------------- W: f32 [K][N] -> sign bf16, transposed to [N][K] ----------------
__global__ __launch_bounds__(256) void conv_w_kernel(const float* __restrict__ W,
                                                     u16* __restrict__ Wt) {
    __shared__ u16 tile[64][72];              // [n_local][k_local], pad 72 for 16B-aligned rows
    const int t  = threadIdx.x;
    const int k0 = (blockIdx.x & 63) * 64;
    const int n0 = (blockIdx.x >> 6) * 64;
#pragma unroll
    for (int i = 0; i < 4; ++i) {
        const int r = i * 16 + (t >> 4);      // k_local
        const int c = (t & 15) * 4;           // n_local
        float4 v = *(const float4*)&W[(size_t)(k0 + r) * 4096 + n0 + c];
        tile[c + 0][r] = (v.x >= 0.f) ? 0x3F80 : 0xBF80;  // +-1.0 bf16
        tile[c + 1][r] = (v.y >= 0.f) ? 0x3F80 : 0xBF80;
        tile[c + 2][r] = (v.z >= 0.f) ? 0x3F80 : 0xBF80;
        tile[c + 3][r] = (v.w >= 0.f) ? 0x3F80 : 0xBF80;
    }
    __syncthreads();
#pragma unroll
    for (int i = 0; i < 2; ++i) {
        const int r = i * 32 + (t >> 3);      // n_local
        const int c = (t & 7) * 8;            // k_local
        ushort8v o;
#pragma unroll
        for (int j = 0; j < 8; ++j) o[j] = tile[r][c + j];
        *(ushort8v*)&Wt[(size_t)(n0 + r) * 4096 + k0 + c] = o;
    }
}

// ---------------- GEMM: 256x256 tile, BK=64, 8-phase + read-ahead pipeline ----------------
// 8 waves (2M x 4N), each owns 128x64 output = acc[8][4] f32x4.
// LDS 128 KiB: buf{0,1} x {A0,A1 | B0,B1} half-regions of 16 KiB (128 rows x 64 bf16).
// 3-bit XOR swizzle: colb ^= (row&7)<<4 (0 bank conflicts, verified r3).
// NEW (r4): fragment ds_reads are issued ONE PHASE AHEAD (post-entry-barrier, pre-MFMA)
// with counted lgkmcnt(N) so LDS service overlaps the MFMA cluster. Read counts per
// phase {4,8,0,12}; stages and vmcnt(4)@p4/p8 unchanged (full hazard ledger re-verified).

#define BAR()        asm volatile("s_barrier" ::: "memory")
#define WAIT_VM4()   asm volatile("s_waitcnt vmcnt(4)" ::: "memory")
#define LGKM(n)      do { asm volatile("s_waitcnt lgkmcnt(" #n ")" ::: "memory"); \
                          __builtin_amdgcn_sched_barrier(0); } while (0)

// stage one half-tile (128 rows x 64 k): 2 x global_load_lds per thread
#define STAGE_A(bufbase, h, koff)                                                   \
    do {                                                                            \
        const char* _s = Asrc + (size_t)(h) * 1048576 + (koff);                     \
        char* _d = lds + (bufbase) + (h) * 16384 + sldsw;                           \
        gload_lds16(_s, _d);                                                        \
        gload_lds16(_s + 524288, _d + 8192);                                        \
    } while (0)
#define STAGE_B(bufbase, h, koff)                                                   \
    do {                                                                            \
        const char* _s = Bsrc + (size_t)(h) * 1048576 + (koff);                     \
        char* _d = lds + (bufbase) + 32768 + (h) * 16384 + sldsw;                   \
        gload_lds16(_s, _d);                                                        \
        gload_lds16(_s + 524288, _d + 8192);                                        \
    } while (0)

// fragment read-ahead macros (8 reads for an A-half, 4 for a B-half)
#define LOAD_A0(bufbase)                                                            \
    do {                                                                            \
        _Pragma("unroll") for (int mi = 0; mi < 4; ++mi)                            \
        _Pragma("unroll") for (int ks = 0; ks < 2; ++ks)                            \
            af0[mi][ks] = *(const short8v*)(lds + (bufbase) + a_rd0 +               \
                                            mi * 2048 + (rdx ^ (ks * 64)));         \
    } while (0)
#define LOAD_A1(bufbase)                                                            \
    do {                                                                            \
        _Pragma("unroll") for (int mi = 0; mi < 4; ++mi)                            \
        _Pragma("unroll") for (int ks = 0; ks < 2; ++ks)                            \
            af1[mi][ks] = *(const short8v*)(lds + (bufbase) + a_rd0 + 8192 +        \
                                            mi * 2048 + (rdx ^ (ks * 64)));         \
    } while (0)
#define LOAD_B0(bufbase)                                                            \
    do {                                                                            \
        _Pragma("unroll") for (int ni = 0; ni < 2; ++ni)                            \
        _Pragma("unroll") for (int ks = 0; ks < 2; ++ks)                            \
            bf0[ni][ks] = *(const short8v*)(lds + (bufbase) + b_rd0 +               \
                                            ni * 2048 + (rdx ^ (ks * 64)));         \
    } while (0)
#define LOAD_B1(bufbase)                                                            \
    do {                                                                            \
        _Pragma("unroll") for (int ni = 0; ni < 2; ++ni)                            \
        _Pragma("unroll") for (int ks = 0; ks < 2; ++ks)                            \
            bf1[ni][ks] = *(const short8v*)(lds + (bufbase) + b_rd0 + 4096 +        \
                                            ni * 2048 + (rdx ^ (ks * 64)));         \
    } while (0)

#define MFMA_Q(AF, BF, mq, nq)                                                      \
    do {                                                                            \
        __builtin_amdgcn_s_setprio(1);                                              \
        _Pragma("unroll") for (int mi = 0; mi < 4; ++mi)                            \
        _Pragma("unroll") for (int ni = 0; ni < 2; ++ni)                            \
        _Pragma("unroll") for (int ks = 0; ks < 2; ++ks)                            \
            acc[(mq) * 4 + mi][(nq) * 2 + ni] = __builtin_amdgcn_mfma_f32_16x16x32_bf16( \
                AF[mi][ks], BF[ni][ks], acc[(mq) * 4 + mi][(nq) * 2 + ni], 0, 0, 0); \
        __builtin_amdgcn_s_setprio(0);                                              \
    } while (0)

__global__ __launch_bounds__(512, 2) void gemm_bin_kernel(const u16* __restrict__ A,
                                                          const u16* __restrict__ Bt,
                                                          const float* __restrict__ bias,
                                                          float* __restrict__ C) {
    __shared__ __attribute__((aligned(1024))) char lds[131072];

    const int bid = blockIdx.x;
    const int swz = (bid & 7) * 32 + (bid >> 3);   // XCD-aware, bijective (256 % 8 == 0)
    const int bm  = swz >> 4;                      // 16x16 tiles
    const int bn  = swz & 15;

    const int tid = threadIdx.x;
    const int w   = tid >> 6;
    const int l   = tid & 63;
    const int wm  = w >> 2;                        // 2 M-waves
    const int wn  = w & 3;                         // 4 N-waves

    // ---- staging addressing (inverse-permuted global source, linear LDS dest) ----
    const int srow = w * 8 + (l >> 3);
    const int scol = ((l & 7) ^ ((l >> 3) & 7)) * 16;
    const char* Asrc = (const char*)A  + (size_t)(bm * 256 + srow) * 8192 + scol;
    const char* Bsrc = (const char*)Bt + (size_t)(bn * 256 + srow) * 8192 + scol;
    const int sldsw = w * 1024;

    // ---- ds_read fragment addressing: row = l&15 (+16*mi...), wanted colb = (l>>4)*16 + ks*64.
    // linear colb = wanted ^ ((row&7)<<4); row&7 == l&7, so per-thread constant:
    const int rdx = (((l >> 4) ^ (l & 7)) << 4);   // ks applied as rdx ^ (ks*64) (bit6, no carry)
    const int a_rd0 = wm * 16384 + (l & 15) * 128;                          // + mi*2048 (+8192 for A1)
    const int b_rd0 = 32768 + (wn >> 1) * 16384 + (wn & 1) * 8192
                    + (l & 15) * 128;                                       // + ni*2048 (+4096 for B1)

    f32x4  acc[8][4] = {};
    short8v af0[4][2], af1[4][2];   // A-half frags (mq=0 / mq=1)
    short8v bf0[2][2], bf1[2][2];   // B-half frags (nq=0 / nq=1)

    // ---- prologue: tile0 all halves + tile1 B halves; land tile0 (leave tile1.B in flight);
    //      then read-ahead the p1 fragments (A0,B0 of buf0).
    STAGE_A(0, 0, 0);      STAGE_A(0, 1, 0);
    STAGE_B(0, 0, 0);      STAGE_B(0, 1, 0);
    STAGE_B(65536, 0, 128); STAGE_B(65536, 1, 128);
    WAIT_VM4();
    BAR();
    LOAD_A0(0); LOAD_B0(0);

    // ---- main loop: 32 iterations x 2 K-tiles (t=2I in buf0, t+1 in buf1) ----
    for (int I = 0; I < 32; ++I) {
        const int koff1 = (2 * I + 1) * 128;          // tile t+1 (A halves, real)
        const int koff2 = ((2 * I + 2) & 63) * 128;   // tile t+2 (wraps to dummy on last iter)
        const int koff3 = ((2 * I + 3) & 63) * 128;   // tile t+3 (dummy on last iter)

        // p1: Q00(buf0); read-ahead B1(buf0); stage A0(t+1)->buf1
        STAGE_A(65536, 0, koff1);
        BAR();
        LOAD_B1(0);
        LGKM(4);                       // drain prologue/p8 reads; B1's 4 stay in flight
        MFMA_Q(af0, bf0, 0, 0);
        BAR();

        // p2: Q01(buf0); read-ahead A1(buf0); stage A1(t+1)->buf1
        STAGE_A(65536, 1, koff1);
        BAR();
        LOAD_A1(0);
        LGKM(8);                       // B1 done; A1's 8 in flight
        MFMA_Q(af0, bf1, 0, 1);
        BAR();

        // p3: Q10(buf0); no new reads; stage B0(t+2)->buf0 (readers drained p2)
        STAGE_B(0, 0, koff2);
        BAR();
        LGKM(0);                       // A1 done
        MFMA_Q(af1, bf0, 1, 0);
        BAR();

        // p4: Q11(buf0); read-ahead A0,B0(buf1) [tile t+1 landed via vm4]; stage B1(t+2)->buf0
        STAGE_B(0, 1, koff2);
        WAIT_VM4();                    // tile t+1 fully landed; tile t+2 B in flight
        BAR();
        LOAD_A0(65536); LOAD_B0(65536);
        LGKM(12);                      // zero-wait: all 12 overlap this MFMA cluster
        MFMA_Q(af1, bf1, 1, 1);
        BAR();

        // p5: Q00(buf1); read-ahead B1(buf1); stage A0(t+2)->buf0
        STAGE_A(0, 0, koff2);
        BAR();
        LOAD_B1(65536);
        LGKM(4);                       // p4's 12 drain; B1's 4 in flight
        MFMA_Q(af0, bf0, 0, 0);
        BAR();

        // p6: Q01(buf1); read-ahead A1(buf1); stage A1(t+2)->buf0
        STAGE_A(0, 1, koff2);
        BAR();
        LOAD_A1(65536);
        LGKM(8);
        MFMA_Q(af0, bf1, 0, 1);
        BAR();

        // p7: Q10(buf1); no new reads; stage B0(t+3)->buf1
        STAGE_B(65536, 0, koff3);
        BAR();
        LGKM(0);
        MFMA_Q(af1, bf0, 1, 0);
        BAR();

        // p8: Q11(buf1); read-ahead A0,B0(buf0, tile t+2) [landed via vm4]; stage B1(t+3)->buf1
        STAGE_B(65536, 1, koff3);
        WAIT_VM4();                    // tile t+2 fully landed; tile t+3 B in flight
        BAR();
        LOAD_A0(0); LOAD_B0(0);
        LGKM(12);                      // zero-wait overlap
        MFMA_Q(af1, bf1, 1, 1);
        BAR();
    }
    asm volatile("s_waitcnt vmcnt(0) lgkmcnt(0)" ::: "memory");   // drain before epilogue

    // ---- epilogue: bias + ReLU + f32 store (C/D layout: col=l&15, row=(l>>4)*4+r) ----
    const int col0 = bn * 256 + wn * 64 + (l & 15);
    const int row0 = bm * 256 + wm * 128 + ((l >> 4) << 2);
#pragma unroll
    for (int n = 0; n < 4; ++n) {
        const float bi = bias[col0 + n * 16];
#pragma unroll
        for (int m = 0; m < 8; ++m) {
#pragma unroll
            for (int r = 0; r < 4; ++r) {
                const float v = acc[m][n][r] + bi;
                C[(size_t)(row0 + m * 16 + r) * 4096 + (col0 + n * 16)] = v > 0.f ? v : 0.f;
            }
        }
    }
}

// ---------------- fallback (only if ws too small): slow but correct ----------------
__global__ __launch_bounds__(256) void fallback_kernel(const float* __restrict__ X,
                                                       const float* __restrict__ W,
                                                       const float* __restrict__ b,
                                                       float* __restrict__ out) {
    __shared__ float xs[16][16];
    __shared__ float ws[16][17];
    const int row = blockIdx.y * 16 + threadIdx.y;
    const int col = blockIdx.x * 16 + threadIdx.x;
    float acc = 0.f;
    for (int k0 = 0; k0 < 4096; k0 += 16) {
        xs[threadIdx.y][threadIdx.x] = X[(size_t)row * 4096 + k0 + threadIdx.x];
        float w = W[(size_t)(k0 + threadIdx.y) * 4096 + col];
        ws[threadIdx.y][threadIdx.x] = (w >= 0.f) ? 1.f : -1.f;
        __syncthreads();
#pragma unroll
        for (int kk = 0; kk < 16; ++kk) acc += xs[threadIdx.y][kk] * ws[kk][threadIdx.x];
        __syncthreads();
    }
    const float v = acc + b[col];
    out[(size_t)row * 4096 + col] = v > 0.f ? v : 0.f;
}

extern "C" void kernel_launch(void* const* d_in, const int* in_sizes, int n_in,
                              void* d_out, int out_size, void* d_ws, size_t ws_size,
                              hipStream_t stream) {
    const float* x = (const float*)d_in[0];
    const float* W = (const float*)d_in[1];
    const float* b = (const float*)d_in[2];
    float* out = (float*)d_out;

    const size_t need = (size_t)2 * 4096 * 4096 * sizeof(u16);   // 64 MB
    if (ws_size < need) {
        fallback_kernel<<<dim3(256, 256), dim3(16, 16), 0, stream>>>(x, W, b, out);
        return;
    }

    u16* Xb = (u16*)d_ws;                       // bf16 x, [4096][4096]
    u16* Wt = Xb + (size_t)4096 * 4096;         // bf16 sign(W)^T, [N][K]

    conv_x_kernel<<<dim3(8192), dim3(256), 0, stream>>>(x, Xb, 4096 * 4096 / 8);
    conv_w_kernel<<<dim3(4096), dim3(256), 0, stream>>>(W, Wt);
    gemm_bin_kernel<<<dim3(256), dim3(512), 0, stream>>>(Xb, Wt, b, out);
}

// Round 5
// 141.266 us; speedup vs baseline: 1.0018x; 1.0018x over previous
//
#include <hip/hip_runtime.h>
#include <hip/hip_bf16.h>

typedef unsigned short u16;
typedef __attribute__((ext_vector_type(8))) short short8v;    // 8 x bf16 (4 VGPR) MFMA A/B frag
typedef __attribute__((ext_vector_type(8))) unsigned short ushort8v;
typedef __attribute__((ext_vector_type(4))) float f32x4;      // MFMA C/D frag

#define GLOBAL_AS __attribute__((address_space(1)))
#define LDS_AS    __attribute__((address_space(3)))

__device__ __forceinline__ void gload_lds16(const void* g, void* l) {
    // 16B/lane direct global->LDS (dest = wave-uniform base + lane*16)
    __builtin_amdgcn_global_load_lds((const GLOBAL_AS unsigned int*)g,
                                     (LDS_AS unsigned int*)l, 16, 0, 0);
}

// ---------------- x: f32 -> bf16 (RNE) ----------------
__global__ __launch_bounds__(256) void conv_x_kernel(const float* __restrict__ X,
                                                     u16* __restrict__ Xb, int n8) {
    int i = blockIdx.x * 256 + threadIdx.x;   // one thread = 8 elements
    if (i >= n8) return;
    const float4* src = (const float4*)X + (size_t)i * 2;
    float4 a = src[0], b = src[1];
    float v[8] = {a.x, a.y, a.z, a.w, b.x, b.y, b.z, b.w};
    ushort8v o;
#pragma unroll
    for (int j = 0; j < 8; ++j) {
        unsigned int u = __builtin_bit_cast(unsigned int, v[j]);
        u += 0x7FFFu + ((u >> 16) & 1u);      // round-to-nearest-even
        o[j] = (u16)(u >> 16);
    }
    *((ushort8v*)Xb + i) = o;
}

// ---------------- W: f32 [K][N] -> sign bf16, transposed to [N][K] ----------------
__global__ __launch_bounds__(256) void conv_w_kernel(const float* __restrict__ W,
                                                     u16* __restrict__ Wt) {
    __shared__ u16 tile[64][72];              // [n_local][k_local], pad 72 for 16B-aligned rows
    const int t  = threadIdx.x;
    const int k0 = (blockIdx.x & 63) * 64;
    const int n0 = (blockIdx.x >> 6) * 64;
#pragma unroll
    for (int i = 0; i < 4; ++i) {
        const int r = i * 16 + (t >> 4);      // k_local
        const int c = (t & 15) * 4;           // n_local
        float4 v = *(const float4*)&W[(size_t)(k0 + r) * 4096 + n0 + c];
        tile[c + 0][r] = (v.x >= 0.f) ? 0x3F80 : 0xBF80;  // +-1.0 bf16
        tile[c + 1][r] = (v.y >= 0.f) ? 0x3F80 : 0xBF80;
        tile[c + 2][r] = (v.z >= 0.f) ? 0x3F80 : 0xBF80;
        tile[c + 3][r] = (v.w >= 0.f) ? 0x3F80 : 0xBF80;
    }
    __syncthreads();
#pragma unroll
    for (int i = 0; i < 2; ++i) {
        const int r = i * 32 + (t >> 3);      // n_local
        const int c = (t & 7) * 8;            // k_local
        ushort8v o;
#pragma unroll
        for (int j = 0; j < 8; ++j) o[j] = tile[r][c + j];
        *(ushort8v*)&Wt[(size_t)(n0 + r) * 4096 + k0 + c] = o;
    }
}

// ---------------- GEMM: 256x256 tile, BK=64, m201-conform 8-phase schedule ----------------
// 8 waves (2M x 4N), each owns 128x64 output = acc[8][4] f32x4.
// LDS 128 KiB: buf{0,1} x {A0,A1 | B0,B1} half-regions of 16 KiB (128 rows x 64 bf16).
// 3-bit XOR swizzle: colb ^= (row&7)<<4 (0 bank conflicts, verified r3).
// r5 change: drop counted-lgkm + sched_barrier walls (m141 failure mode). Phase = m201
// template: [ds_read current frags; stage; (opt lgkm(8)); s_barrier; lgkm(0); setprio;
// 16 MFMA; setprio; s_barrier]. Only the two vmcnt(4) fences carry "memory" clobbers —
// they are the exact hazard points; everything else is free for the scheduler to
// interleave into the MFMA clusters.

#define BAR()        __builtin_amdgcn_s_barrier()
#define LGKM0()      asm volatile("s_waitcnt lgkmcnt(0)")
#define LGKM8()      asm volatile("s_waitcnt lgkmcnt(8)")
#define WAIT_VM4()   asm volatile("s_waitcnt vmcnt(4)" ::: "memory")

// stage one half-tile (128 rows x 64 k): 2 x global_load_lds per thread
#define STAGE_A(bufbase, h, koff)                                                   \
    do {                                                                            \
        const char* _s = Asrc + (size_t)(h) * 1048576 + (koff);                     \
        char* _d = lds + (bufbase) + (h) * 16384 + sldsw;                           \
        gload_lds16(_s, _d);                                                        \
        gload_lds16(_s + 524288, _d + 8192);                                        \
    } while (0)
#define STAGE_B(bufbase, h, koff)                                                   \
    do {                                                                            \
        const char* _s = Bsrc + (size_t)(h) * 1048576 + (koff);                     \
        char* _d = lds + (bufbase) + 32768 + (h) * 16384 + sldsw;                   \
        gload_lds16(_s, _d);                                                        \
        gload_lds16(_s + 524288, _d + 8192);                                        \
    } while (0)

// fragment read macros (8 reads for an A-half, 4 for a B-half)
#define LOAD_A0(bufbase)                                                            \
    do {                                                                            \
        _Pragma("unroll") for (int mi = 0; mi < 4; ++mi)                            \
        _Pragma("unroll") for (int ks = 0; ks < 2; ++ks)                            \
            af0[mi][ks] = *(const short8v*)(lds + (bufbase) + a_rd0 +               \
                                            mi * 2048 + (rdx ^ (ks * 64)));         \
    } while (0)
#define LOAD_A1(bufbase)                                                            \
    do {                                                                            \
        _Pragma("unroll") for (int mi = 0; mi < 4; ++mi)                            \
        _Pragma("unroll") for (int ks = 0; ks < 2; ++ks)                            \
            af1[mi][ks] = *(const short8v*)(lds + (bufbase) + a_rd0 + 8192 +        \
                                            mi * 2048 + (rdx ^ (ks * 64)));         \
    } while (0)
#define LOAD_B0(bufbase)                                                            \
    do {                                                                            \
        _Pragma("unroll") for (int ni = 0; ni < 2; ++ni)                            \
        _Pragma("unroll") for (int ks = 0; ks < 2; ++ks)                            \
            bf0[ni][ks] = *(const short8v*)(lds + (bufbase) + b_rd0 +               \
                                            ni * 2048 + (rdx ^ (ks * 64)));         \
    } while (0)
#define LOAD_B1(bufbase)                                                            \
    do {                                                                            \
        _Pragma("unroll") for (int ni = 0; ni < 2; ++ni)                            \
        _Pragma("unroll") for (int ks = 0; ks < 2; ++ks)                            \
            bf1[ni][ks] = *(const short8v*)(lds + (bufbase) + b_rd0 + 4096 +        \
                                            ni * 2048 + (rdx ^ (ks * 64)));         \
    } while (0)

#define MFMA_Q(AF, BF, mq, nq)                                                      \
    do {                                                                            \
        __builtin_amdgcn_s_setprio(1);                                              \
        _Pragma("unroll") for (int mi = 0; mi < 4; ++mi)                            \
        _Pragma("unroll") for (int ni = 0; ni < 2; ++ni)                            \
        _Pragma("unroll") for (int ks = 0; ks < 2; ++ks)                            \
            acc[(mq) * 4 + mi][(nq) * 2 + ni] = __builtin_amdgcn_mfma_f32_16x16x32_bf16( \
                AF[mi][ks], BF[ni][ks], acc[(mq) * 4 + mi][(nq) * 2 + ni], 0, 0, 0); \
        __builtin_amdgcn_s_setprio(0);                                              \
    } while (0)

__global__ __launch_bounds__(512, 2) void gemm_bin_kernel(const u16* __restrict__ A,
                                                          const u16* __restrict__ Bt,
                                                          const float* __restrict__ bias,
                                                          float* __restrict__ C) {
    __shared__ __attribute__((aligned(1024))) char lds[131072];

    const int bid = blockIdx.x;
    const int swz = (bid & 7) * 32 + (bid >> 3);   // XCD-aware, bijective (256 % 8 == 0)
    const int bm  = swz >> 4;                      // 16x16 tiles
    const int bn  = swz & 15;

    const int tid = threadIdx.x;
    const int w   = tid >> 6;
    const int l   = tid & 63;
    const int wm  = w >> 2;                        // 2 M-waves
    const int wn  = w & 3;                         // 4 N-waves

    // ---- staging addressing (inverse-permuted global source, linear LDS dest) ----
    const int srow = w * 8 + (l >> 3);
    const int scol = ((l & 7) ^ ((l >> 3) & 7)) * 16;
    const char* Asrc = (const char*)A  + (size_t)(bm * 256 + srow) * 8192 + scol;
    const char* Bsrc = (const char*)Bt + (size_t)(bn * 256 + srow) * 8192 + scol;
    const int sldsw = w * 1024;

    // ---- ds_read fragment addressing: row = l&15 (+16*mi...), wanted colb = (l>>4)*16 + ks*64.
    // linear colb = wanted ^ ((row&7)<<4); row&7 == l&7, so per-thread constant:
    const int rdx = (((l >> 4) ^ (l & 7)) << 4);   // ks applied as rdx ^ (ks*64) (bit6, no carry)
    const int a_rd0 = wm * 16384 + (l & 15) * 128;                          // + mi*2048 (+8192 for A1)
    const int b_rd0 = 32768 + (wn >> 1) * 16384 + (wn & 1) * 8192
                    + (l & 15) * 128;                                       // + ni*2048 (+4096 for B1)

    f32x4  acc[8][4] = {};
    short8v af0[4][2], af1[4][2];   // A-half frags (mq=0 / mq=1)
    short8v bf0[2][2], bf1[2][2];   // B-half frags (nq=0 / nq=1)

    // ---- prologue: tile0 all halves + tile1 B halves; land tile0 (leave tile1.B in flight) ----
    STAGE_A(0, 0, 0);      STAGE_A(0, 1, 0);
    STAGE_B(0, 0, 0);      STAGE_B(0, 1, 0);
    STAGE_B(65536, 0, 128); STAGE_B(65536, 1, 128);
    WAIT_VM4();
    BAR();

    // ---- main loop: 32 iterations x 2 K-tiles (t=2I in buf0, t+1 in buf1) ----
    // Stage plan (1 half-tile/phase): p1,p2: A0,A1(t+1)->buf1; p3,p4: B0,B1(t+2)->buf0;
    // p5,p6: A0,A1(t+2)->buf0; p7,p8: B0,B1(t+3)->buf1. vmcnt(4) fences at p4/p8 are the
    // land-guards for every read of the following 4 phases (ledger verified r5).
    for (int I = 0; I < 32; ++I) {
        const int koff1 = (2 * I + 1) * 128;          // tile t+1 (A halves, real)
        const int koff2 = ((2 * I + 2) & 63) * 128;   // tile t+2 (wraps to dummy on last iter)
        const int koff3 = ((2 * I + 3) & 63) * 128;   // tile t+3 (dummy on last iter)

        // p1: Q00(buf0) — read af0,bf0(buf0); stage A0(t+1)->buf1
        LOAD_A0(0); LOAD_B0(0);
        STAGE_A(65536, 0, koff1);
        LGKM8();
        BAR(); LGKM0();
        MFMA_Q(af0, bf0, 0, 0);
        BAR();

        // p2: Q01(buf0) — read bf1(buf0); stage A1(t+1)->buf1
        LOAD_B1(0);
        STAGE_A(65536, 1, koff1);
        BAR(); LGKM0();
        MFMA_Q(af0, bf1, 0, 1);
        BAR();

        // p3: Q10(buf0) — read af1(buf0); stage B0(t+2)->buf0 (B0 readers done p1)
        LOAD_A1(0);
        STAGE_B(0, 0, koff2);
        BAR(); LGKM0();
        MFMA_Q(af1, bf0, 1, 0);
        BAR();

        // p4: Q11(buf0) — no reads; stage B1(t+2)->buf0; vmcnt fence (lands t+1 fully)
        STAGE_B(0, 1, koff2);
        WAIT_VM4();
        BAR();
        MFMA_Q(af1, bf1, 1, 1);
        BAR();

        // p5: Q00(buf1) — read af0,bf0(buf1); stage A0(t+2)->buf0
        LOAD_A0(65536); LOAD_B0(65536);
        STAGE_A(0, 0, koff2);
        LGKM8();
        BAR(); LGKM0();
        MFMA_Q(af0, bf0, 0, 0);
        BAR();

        // p6: Q01(buf1) — read bf1(buf1); stage A1(t+2)->buf0
        LOAD_B1(65536);
        STAGE_A(0, 1, koff2);
        BAR(); LGKM0();
        MFMA_Q(af0, bf1, 0, 1);
        BAR();

        // p7: Q10(buf1) — read af1(buf1); stage B0(t+3)->buf1
        LOAD_A1(65536);
        STAGE_B(65536, 0, koff3);
        BAR(); LGKM0();
        MFMA_Q(af1, bf0, 1, 0);
        BAR();

        // p8: Q11(buf1) — no reads; stage B1(t+3)->buf1; vmcnt fence (lands t+2 fully)
        STAGE_B(65536, 1, koff3);
        WAIT_VM4();
        BAR();
        MFMA_Q(af1, bf1, 1, 1);
        BAR();
    }
    asm volatile("s_waitcnt vmcnt(0) lgkmcnt(0)" ::: "memory");   // drain before epilogue

    // ---- epilogue: bias + ReLU + f32 store (C/D layout: col=l&15, row=(l>>4)*4+r) ----
    const int col0 = bn * 256 + wn * 64 + (l & 15);
    const int row0 = bm * 256 + wm * 128 + ((l >> 4) << 2);
#pragma unroll
    for (int n = 0; n < 4; ++n) {
        const float bi = bias[col0 + n * 16];
#pragma unroll
        for (int m = 0; m < 8; ++m) {
#pragma unroll
            for (int r = 0; r < 4; ++r) {
                const float v = acc[m][n][r] + bi;
                C[(size_t)(row0 + m * 16 + r) * 4096 + (col0 + n * 16)] = v > 0.f ? v : 0.f;
            }
        }
    }
}

// ---------------- fallback (only if ws too small): slow but correct ----------------
__global__ __launch_bounds__(256) void fallback_kernel(const float* __restrict__ X,
                                                       const float* __restrict__ W,
                                                       const float* __restrict__ b,
                                                       float* __restrict__ out) {
    __shared__ float xs[16][16];
    __shared__ float ws[16][17];
    const int row = blockIdx.y * 16 + threadIdx.y;
    const int col = blockIdx.x * 16 + threadIdx.x;
    float acc = 0.f;
    for (int k0 = 0; k0 < 4096; k0 += 16) {
        xs[threadIdx.y][threadIdx.x] = X[(size_t)row * 4096 + k0 + threadIdx.x];
        float w = W[(size_t)(k0 + threadIdx.y) * 4096 + col];
        ws[threadIdx.y][threadIdx.x] = (w >= 0.f) ? 1.f : -1.f;
        __syncthreads();
#pragma unroll
        for (int kk = 0; kk < 16; ++kk) acc += xs[threadIdx.y][kk] * ws[kk][threadIdx.x];
        __syncthreads();
    }
    const float v = acc + b[col];
    out[(size_t)row * 4096 + col] = v > 0.f ? v : 0.f;
}

extern "C" void kernel_launch(void* const* d_in, const int* in_sizes, int n_in,
                              void* d_out, int out_size, void* d_ws, size_t ws_size,
                              hipStream_t stream) {
    const float* x = (const float*)d_in[0];
    const float* W = (const float*)d_in[1];
    const float* b = (const float*)d_in[2];
    float* out = (float*)d_out;

    const size_t need = (size_t)2 * 4096 * 4096 * sizeof(u16);   // 64 MB
    if (ws_size < need) {
        fallback_kernel<<<dim3(256, 256), dim3(16, 16), 0, stream>>>(x, W, b, out);
        return;
    }

    u16* Xb = (u16*)d_ws;                       // bf16 x, [4096][4096]
    u16* Wt = Xb + (size_t)4096 * 4096;         // bf16 sign(W)^T, [N][K]

    conv_x_kernel<<<dim3(8192), dim3(256), 0, stream>>>(x, Xb, 4096 * 4096 / 8);
    conv_w_kernel<<<dim3(4096), dim3(256), 0, stream>>>(W, Wt);
    gemm_bin_kernel<<<dim3(256), dim3(512), 0, stream>>>(Xb, Wt, b, out);
}

// Round 6
// 93.224 us; speedup vs baseline: 1.5180x; 1.5153x over previous
//
#include <hip/hip_runtime.h>
#include <hip/hip_bf16.h>

typedef unsigned short u16;
typedef signed char i8;
typedef __attribute__((ext_vector_type(4))) int   int4v;   // 16 x i8 MFMA A/B frag, or i32x4 C/D
typedef __attribute__((ext_vector_type(4))) float f32x4;

#define GLOBAL_AS __attribute__((address_space(1)))
#define LDS_AS    __attribute__((address_space(3)))

__device__ __forceinline__ void gload_lds16(const void* g, void* l) {
    // 16B/lane direct global->LDS (dest = wave-uniform base + lane*16)
    __builtin_amdgcn_global_load_lds((const GLOBAL_AS unsigned int*)g,
                                     (LDS_AS unsigned int*)l, 16, 0, 0);
}

// ---------------- x: f32 -> i8, per-row symmetric quant; inv_s[row] = rowmax/127 ----------------
__global__ __launch_bounds__(256) void quant_x_kernel(const float* __restrict__ X,
                                                      i8* __restrict__ Xq,
                                                      float* __restrict__ inv_s) {
    const int row = blockIdx.x;
    const int t   = threadIdx.x;
    const float4* src = (const float4*)(X + (size_t)row * 4096 + t * 16);
    float4 v0 = src[0], v1 = src[1], v2 = src[2], v3 = src[3];
    float vals[16] = {v0.x, v0.y, v0.z, v0.w, v1.x, v1.y, v1.z, v1.w,
                      v2.x, v2.y, v2.z, v2.w, v3.x, v3.y, v3.z, v3.w};
    float m = 0.f;
#pragma unroll
    for (int j = 0; j < 16; ++j) m = fmaxf(m, fabsf(vals[j]));
#pragma unroll
    for (int off = 32; off; off >>= 1) m = fmaxf(m, __shfl_xor(m, off));
    __shared__ float sm[4];
    if ((t & 63) == 0) sm[t >> 6] = m;
    __syncthreads();
    m = fmaxf(fmaxf(sm[0], sm[1]), fmaxf(sm[2], sm[3]));
    const float s = (m > 0.f) ? 127.0f / m : 0.f;
    uint4 packed;
    unsigned int* pw = (unsigned int*)&packed;
#pragma unroll
    for (int g = 0; g < 4; ++g) {
        unsigned int wd = 0;
#pragma unroll
        for (int j = 0; j < 4; ++j) {
            int q = (int)rintf(vals[g * 4 + j] * s);   // |q| <= 127 by construction
            wd |= ((unsigned int)(q & 255)) << (8 * j);
        }
        pw[g] = wd;
    }
    ((uint4*)(Xq + (size_t)row * 4096))[t] = packed;
    if (t == 0) inv_s[row] = m * (1.0f / 127.0f);
}

// ---------------- W: f32 [K][N] -> sign i8 (+-1), transposed to [N][K] ----------------
__global__ __launch_bounds__(256) void conv_w_kernel(const float* __restrict__ W,
                                                     i8* __restrict__ Wt) {
    __shared__ __attribute__((aligned(16))) i8 tile[64][80];   // [n_local][k_local], 80 = 5*16
    const int t  = threadIdx.x;
    const int k0 = (blockIdx.x & 63) * 64;
    const int n0 = (blockIdx.x >> 6) * 64;
#pragma unroll
    for (int i = 0; i < 4; ++i) {
        const int r = i * 16 + (t >> 4);      // k_local
        const int c = (t & 15) * 4;           // n_local
        float4 v = *(const float4*)&W[(size_t)(k0 + r) * 4096 + n0 + c];
        tile[c + 0][r] = (v.x >= 0.f) ? 1 : -1;
        tile[c + 1][r] = (v.y >= 0.f) ? 1 : -1;
        tile[c + 2][r] = (v.z >= 0.f) ? 1 : -1;
        tile[c + 3][r] = (v.w >= 0.f) ? 1 : -1;
    }
    __syncthreads();
    const int r = t >> 2;                     // n_local 0..63
    const int c = (t & 3) * 16;               // k_local 16B chunk
    *(int4*)&Wt[(size_t)(n0 + r) * 4096 + k0 + c] = *(const int4*)&tile[r][c];
}

// ---------------- GEMM: i8 256x256 tile, BK=128, 8-phase schedule ----------------
// Byte-identical memory engine to the verified bf16 r3/r5 kernel (regions 128 rows x 128 B,
// 3-bit XOR swizzle -> 0 bank conflicts, 2 gloads/stage, vmcnt(4)@p4/p8). Only dtype changed:
// K-tile = 128 i8 elems (was 64 bf16) = same 128 B. MFMA = i32_16x16x64_i8 (2x bf16 rate).
// Epilogue dequant: out = acc_i32 * inv_s[row] + bias, relu.

#define BAR()        __builtin_amdgcn_s_barrier()
#define LGKM0()      asm volatile("s_waitcnt lgkmcnt(0)")
#define LGKM8()      asm volatile("s_waitcnt lgkmcnt(8)")
#define WAIT_VM4()   asm volatile("s_waitcnt vmcnt(4)" ::: "memory")

// stage one half-tile (128 rows x 128 B): 2 x global_load_lds per thread
#define STAGE_A(bufbase, h, koff)                                                   \
    do {                                                                            \
        const char* _s = Asrc + (size_t)(h) * 524288 + (koff);                      \
        char* _d = lds + (bufbase) + (h) * 16384 + sldsw;                           \
        gload_lds16(_s, _d);                                                        \
        gload_lds16(_s + 262144, _d + 8192);                                        \
    } while (0)
#define STAGE_B(bufbase, h, koff)                                                   \
    do {                                                                            \
        const char* _s = Bsrc + (size_t)(h) * 524288 + (koff);                      \
        char* _d = lds + (bufbase) + 32768 + (h) * 16384 + sldsw;                   \
        gload_lds16(_s, _d);                                                        \
        gload_lds16(_s + 262144, _d + 8192);                                        \
    } while (0)

// fragment read macros (8 reads for an A-half, 4 for a B-half); 16B = 16 K-elems i8
#define LOAD_A0(bufbase)                                                            \
    do {                                                                            \
        _Pragma("unroll") for (int mi = 0; mi < 4; ++mi)                            \
        _Pragma("unroll") for (int ks = 0; ks < 2; ++ks)                            \
            af0[mi][ks] = *(const int4v*)(lds + (bufbase) + a_rd0 +                 \
                                          mi * 2048 + (rdx ^ (ks * 64)));           \
    } while (0)
#define LOAD_A1(bufbase)                                                            \
    do {                                                                            \
        _Pragma("unroll") for (int mi = 0; mi < 4; ++mi)                            \
        _Pragma("unroll") for (int ks = 0; ks < 2; ++ks)                            \
            af1[mi][ks] = *(const int4v*)(lds + (bufbase) + a_rd0 + 8192 +          \
                                          mi * 2048 + (rdx ^ (ks * 64)));           \
    } while (0)
#define LOAD_B0(bufbase)                                                            \
    do {                                                                            \
        _Pragma("unroll") for (int ni = 0; ni < 2; ++ni)                            \
        _Pragma("unroll") for (int ks = 0; ks < 2; ++ks)                            \
            bf0[ni][ks] = *(const int4v*)(lds + (bufbase) + b_rd0 +                 \
                                          ni * 2048 + (rdx ^ (ks * 64)));           \
    } while (0)
#define LOAD_B1(bufbase)                                                            \
    do {                                                                            \
        _Pragma("unroll") for (int ni = 0; ni < 2; ++ni)                            \
        _Pragma("unroll") for (int ks = 0; ks < 2; ++ks)                            \
            bf1[ni][ks] = *(const int4v*)(lds + (bufbase) + b_rd0 + 4096 +          \
                                          ni * 2048 + (rdx ^ (ks * 64)));           \
    } while (0)

#define MFMA_Q(AF, BF, mq, nq)                                                      \
    do {                                                                            \
        __builtin_amdgcn_s_setprio(1);                                              \
        _Pragma("unroll") for (int mi = 0; mi < 4; ++mi)                            \
        _Pragma("unroll") for (int ni = 0; ni < 2; ++ni)                            \
        _Pragma("unroll") for (int ks = 0; ks < 2; ++ks)                            \
            acc[(mq) * 4 + mi][(nq) * 2 + ni] = __builtin_amdgcn_mfma_i32_16x16x64_i8( \
                AF[mi][ks], BF[ni][ks], acc[(mq) * 4 + mi][(nq) * 2 + ni], 0, 0, 0); \
        __builtin_amdgcn_s_setprio(0);                                              \
    } while (0)

__global__ __launch_bounds__(512, 2) void gemm_bin_kernel(const i8* __restrict__ A,
                                                          const i8* __restrict__ Bt,
                                                          const float* __restrict__ bias,
                                                          const float* __restrict__ inv_s,
                                                          float* __restrict__ C) {
    __shared__ __attribute__((aligned(1024))) char lds[131072];

    const int bid = blockIdx.x;
    const int swz = (bid & 7) * 32 + (bid >> 3);   // XCD-aware, bijective (256 % 8 == 0)
    const int bm  = swz >> 4;                      // 16x16 tiles
    const int bn  = swz & 15;

    const int tid = threadIdx.x;
    const int w   = tid >> 6;
    const int l   = tid & 63;
    const int wm  = w >> 2;                        // 2 M-waves
    const int wn  = w & 3;                         // 4 N-waves

    // ---- staging addressing (inverse-permuted global source, linear LDS dest) ----
    const int srow = w * 8 + (l >> 3);
    const int scol = ((l & 7) ^ ((l >> 3) & 7)) * 16;
    const char* Asrc = (const char*)A  + (size_t)(bm * 256 + srow) * 4096 + scol;
    const char* Bsrc = (const char*)Bt + (size_t)(bn * 256 + srow) * 4096 + scol;
    const int sldsw = w * 1024;

    // ---- ds_read fragment addressing (identical bytes to bf16 version) ----
    const int rdx = (((l >> 4) ^ (l & 7)) << 4);
    const int a_rd0 = wm * 16384 + (l & 15) * 128;
    const int b_rd0 = 32768 + (wn >> 1) * 16384 + (wn & 1) * 8192 + (l & 15) * 128;

    int4v acc[8][4] = {};
    int4v af0[4][2], af1[4][2];   // A-half frags (mq=0 / mq=1)
    int4v bf0[2][2], bf1[2][2];   // B-half frags (nq=0 / nq=1)

    // ---- prologue: tile0 all halves + tile1 B halves; land tile0 (tile1.B in flight) ----
    STAGE_A(0, 0, 0);      STAGE_A(0, 1, 0);
    STAGE_B(0, 0, 0);      STAGE_B(0, 1, 0);
    STAGE_B(65536, 0, 128); STAGE_B(65536, 1, 128);
    WAIT_VM4();
    BAR();

    // ---- main loop: 16 iterations x 2 K-tiles (K-tile = 128 i8 = 128 B) ----
    for (int I = 0; I < 16; ++I) {
        const int koff1 = (2 * I + 1) * 128;          // tile t+1 (A halves, real)
        const int koff2 = ((2 * I + 2) & 31) * 128;   // tile t+2 (wraps to dummy on last iter)
        const int koff3 = ((2 * I + 3) & 31) * 128;   // tile t+3 (dummy on last iter)

        // p1: Q00(buf0) — read af0,bf0(buf0); stage A0(t+1)->buf1
        LOAD_A0(0); LOAD_B0(0);
        STAGE_A(65536, 0, koff1);
        LGKM8();
        BAR(); LGKM0();
        MFMA_Q(af0, bf0, 0, 0);
        BAR();

        // p2: Q01(buf0) — read bf1(buf0); stage A1(t+1)->buf1
        LOAD_B1(0);
        STAGE_A(65536, 1, koff1);
        BAR(); LGKM0();
        MFMA_Q(af0, bf1, 0, 1);
        BAR();

        // p3: Q10(buf0) — read af1(buf0); stage B0(t+2)->buf0
        LOAD_A1(0);
        STAGE_B(0, 0, koff2);
        BAR(); LGKM0();
        MFMA_Q(af1, bf0, 1, 0);
        BAR();

        // p4: Q11(buf0) — stage B1(t+2)->buf0; vmcnt fence (lands t+1 fully)
        STAGE_B(0, 1, koff2);
        WAIT_VM4();
        BAR();
        MFMA_Q(af1, bf1, 1, 1);
        BAR();

        // p5: Q00(buf1) — read af0,bf0(buf1); stage A0(t+2)->buf0
        LOAD_A0(65536); LOAD_B0(65536);
        STAGE_A(0, 0, koff2);
        LGKM8();
        BAR(); LGKM0();
        MFMA_Q(af0, bf0, 0, 0);
        BAR();

        // p6: Q01(buf1) — read bf1(buf1); stage A1(t+2)->buf0
        LOAD_B1(65536);
        STAGE_A(0, 1, koff2);
        BAR(); LGKM0();
        MFMA_Q(af0, bf1, 0, 1);
        BAR();

        // p7: Q10(buf1) — read af1(buf1); stage B0(t+3)->buf1
        LOAD_A1(65536);
        STAGE_B(65536, 0, koff3);
        BAR(); LGKM0();
        MFMA_Q(af1, bf0, 1, 0);
        BAR();

        // p8: Q11(buf1) — stage B1(t+3)->buf1; vmcnt fence (lands t+2 fully)
        STAGE_B(65536, 1, koff3);
        WAIT_VM4();
        BAR();
        MFMA_Q(af1, bf1, 1, 1);
        BAR();
    }
    asm volatile("s_waitcnt vmcnt(0) lgkmcnt(0)" ::: "memory");   // drain before epilogue

    // ---- epilogue: dequant + bias + ReLU + f32 store (C/D: col=l&15, row=(l>>4)*4+r) ----
    const int col0 = bn * 256 + wn * 64 + (l & 15);
    const int row0 = bm * 256 + wm * 128 + ((l >> 4) << 2);
    float bn4[4];
#pragma unroll
    for (int n = 0; n < 4; ++n) bn4[n] = bias[col0 + n * 16];
#pragma unroll
    for (int m = 0; m < 8; ++m) {
#pragma unroll
        for (int r = 0; r < 4; ++r) {
            const int  grow = row0 + m * 16 + r;
            const float ivs = inv_s[grow];
#pragma unroll
            for (int n = 0; n < 4; ++n) {
                const float v = (float)acc[m][n][r] * ivs + bn4[n];
                C[(size_t)grow * 4096 + (col0 + n * 16)] = v > 0.f ? v : 0.f;
            }
        }
    }
}

// ---------------- fallback (only if ws too small): slow but correct ----------------
__global__ __launch_bounds__(256) void fallback_kernel(const float* __restrict__ X,
                                                       const float* __restrict__ W,
                                                       const float* __restrict__ b,
                                                       float* __restrict__ out) {
    __shared__ float xs[16][16];
    __shared__ float ws[16][17];
    const int row = blockIdx.y * 16 + threadIdx.y;
    const int col = blockIdx.x * 16 + threadIdx.x;
    float acc = 0.f;
    for (int k0 = 0; k0 < 4096; k0 += 16) {
        xs[threadIdx.y][threadIdx.x] = X[(size_t)row * 4096 + k0 + threadIdx.x];
        float w = W[(size_t)(k0 + threadIdx.y) * 4096 + col];
        ws[threadIdx.y][threadIdx.x] = (w >= 0.f) ? 1.f : -1.f;
        __syncthreads();
#pragma unroll
        for (int kk = 0; kk < 16; ++kk) acc += xs[threadIdx.y][kk] * ws[kk][threadIdx.x];
        __syncthreads();
    }
    const float v = acc + b[col];
    out[(size_t)row * 4096 + col] = v > 0.f ? v : 0.f;
}

extern "C" void kernel_launch(void* const* d_in, const int* in_sizes, int n_in,
                              void* d_out, int out_size, void* d_ws, size_t ws_size,
                              hipStream_t stream) {
    const float* x = (const float*)d_in[0];
    const float* W = (const float*)d_in[1];
    const float* b = (const float*)d_in[2];
    float* out = (float*)d_out;

    const size_t need = (size_t)32 * 1024 * 1024 + 64 * 1024;   // 2x16MB i8 + 16KB scales
    if (ws_size < need) {
        fallback_kernel<<<dim3(256, 256), dim3(16, 16), 0, stream>>>(x, W, b, out);
        return;
    }

    i8*    Xq  = (i8*)d_ws;                                     // i8 x, [4096][4096]
    i8*    Wt  = Xq + (size_t)4096 * 4096;                      // i8 sign(W)^T, [N][K]
    float* ivs = (float*)(Xq + (size_t)2 * 4096 * 4096);        // per-row inv scale

    quant_x_kernel<<<dim3(4096), dim3(256), 0, stream>>>(x, Xq, ivs);
    conv_w_kernel<<<dim3(4096), dim3(256), 0, stream>>>(W, Wt);
    gemm_bin_kernel<<<dim3(256), dim3(512), 0, stream>>>(Xq, Wt, b, ivs, out);
}